// Round 2
// baseline (455.382 us; speedup 1.0000x reference)
//
#include <hip/hip_runtime.h>
#include <stdint.h>

typedef unsigned short u16;
typedef __bf16 bf16x8 __attribute__((ext_vector_type(8)));
typedef float f32x4 __attribute__((ext_vector_type(4)));

#define B_N   16
#define C_CH  128
#define O_CH  256
#define HW    56
#define PH    58
#define PW    72

#define GLOBAL_AS __attribute__((address_space(1)))
#define LDS_AS    __attribute__((address_space(3)))

__device__ __forceinline__ void glds16(const u16* g, u16* l) {
    __builtin_amdgcn_global_load_lds((const GLOBAL_AS void*)g, (LDS_AS void*)l, 16, 0, 0);
}

// ---------------------------------------------------------------------------
// prep1: quantize + zero-pad + NCHW->NHWC transpose.
//   xp[b][hp][wp][c] (hp in [0,58), wp in [0,72), c in [0,128)) as bf16 bits.
// One block per (b, hp). LDS tile Lt[c][w] padded to 58 w-slots so the
// write-phase read (stride 116 B -> bank stride 29, coprime with 32) is
// conflict-free.
// ---------------------------------------------------------------------------
__global__ __launch_bounds__(256) void quant_pad(const float* __restrict__ x,
                                                 u16* __restrict__ xp) {
    __shared__ u16 Lt[C_CH][58];
    const int hp = blockIdx.x;
    const int b = blockIdx.y;
    const int tid = threadIdx.x;
    const int h = hp - 1;
    const bool interior = (unsigned)h < HW;

    if (interior) {
        // read x[b][c][h][w] coalesced (w fastest), quantize, Lt[c][w]
        for (int i = 0; i < 28; ++i) {
            int idx = i * 256 + tid;             // 128*56 = 7168 elements
            int c = idx / HW, w = idx % HW;
            float v = x[((b * C_CH + c) * HW + h) * HW + w];
            float q = fminf(fmaxf(rintf(v * 255.0f), 0.0f), 255.0f);
            Lt[c][w] = (u16)(__float_as_uint(q) >> 16);
        }
    }
    __syncthreads();
    // write xp[b][hp][wp][c] coalesced (c fastest), zeros in the pad
    u16* dst = xp + ((size_t)(b * PH + hp) * PW) * C_CH;
    for (int j = 0; j < 36; ++j) {
        int idx = j * 256 + tid;                 // 72*128 = 9216 elements
        int wp = idx / C_CH, c = idx % C_CH;
        int w = wp - 1;
        u16 bits = 0;
        if (interior && (unsigned)w < HW) bits = Lt[c][w];
        dst[idx] = bits;
    }
}

// ---------------------------------------------------------------------------
// prep2: Bq[r][o][c] = bf16bits( pcilt[o][c][r][1] )   (r = kh*3+kw)
// ---------------------------------------------------------------------------
__global__ __launch_bounds__(256) void make_w(const float* __restrict__ pcilt,
                                              u16* __restrict__ Bq) {
    int idx = blockIdx.x * 256 + threadIdx.x;    // total = 9*256*128
    int c = idx % C_CH;
    int o = (idx / C_CH) % O_CH;
    int r = idx / (C_CH * O_CH);
    float v = pcilt[(size_t)(((o * C_CH + c) * 9 + r)) * 256 + 1];
    Bq[idx] = (u16)(__float_as_uint(v) >> 16);
}

// ---------------------------------------------------------------------------
// conv as implicit GEMM:  D[o][m] = sum_k W[o][k] * Im[k][m]
//   k = r*128 + c ; m-tile(128) = dh*64 + w(0..63) for one (b, h0).
// Staging: global_load_lds width=16. Wave `wid` owns k-subgroup kcg=wid for
// both tiles; per 32-k chunk it issues 4 one-instruction loads (Is mh=0/1,
// Ws oh=0/1), each 64 lanes x 16 B with LDS dest = uniform base + lane*16.
// ---------------------------------------------------------------------------
__global__ __launch_bounds__(256) void conv_mfma(const u16* __restrict__ xp,
                                                 const u16* __restrict__ Bq,
                                                 const float* __restrict__ bias,
                                                 float* __restrict__ out) {
    __shared__ __align__(16) u16 Ws[4][128][8];   // [kcg][o][kce]  8 KB
    __shared__ __align__(16) u16 Is[4][128][8];   // [kcg][m][kce]  8 KB

    const int tid = threadIdx.x;
    const int o_blk = blockIdx.x * 128;
    const int h0 = blockIdx.y * 2;
    const int b = blockIdx.z;

    const int lane = tid & 63;
    const int wid = tid >> 6;
    const int wo = wid & 1;    // o half for compute
    const int wm = wid >> 1;   // m half (== dh) for compute

    f32x4 acc[4][4];
#pragma unroll
    for (int i = 0; i < 4; i++)
#pragma unroll
        for (int j = 0; j < 4; j++) acc[i][j] = (f32x4){0.f, 0.f, 0.f, 0.f};

    // staging pointers (per lane); element offsets, contiguous c innermost
    const u16* pI0 = xp + ((size_t)(b * PH + h0) * PW + lane) * C_CH + wid * 8;
    const u16* pI1 = pI0 + (size_t)PW * C_CH;                 // dh = 1
    const u16* pW0 = Bq + (size_t)(o_blk + lane) * C_CH + wid * 8;
    const u16* pW1 = pW0 + 64 * C_CH;
    u16* lI0 = &Is[wid][0][0];
    u16* lI1 = &Is[wid][64][0];
    u16* lW0 = &Ws[wid][0][0];
    u16* lW1 = &Ws[wid][64][0];

    const int quad = lane >> 4;
    const int lrow = lane & 15;

    for (int r = 0; r < 9; ++r) {
        const int kh = r / 3, kw = r % 3;
        const int offI_r = (kh * PW + kw) * C_CH;
        const int offW_r = r * O_CH * C_CH;
#pragma unroll
        for (int cc = 0; cc < 4; ++cc) {
            const int offI = offI_r + cc * 32;
            const int offW = offW_r + cc * 32;
            __syncthreads();
            glds16(pI0 + offI, lI0);
            glds16(pI1 + offI, lI1);
            glds16(pW0 + offW, lW0);
            glds16(pW1 + offW, lW1);
            __syncthreads();

            bf16x8 af[4], bfr[4];
#pragma unroll
            for (int i = 0; i < 4; i++)
                af[i] = *(const bf16x8*)&Ws[quad][wo * 64 + i * 16 + lrow][0];
#pragma unroll
            for (int j = 0; j < 4; j++)
                bfr[j] = *(const bf16x8*)&Is[quad][wm * 64 + j * 16 + lrow][0];
#pragma unroll
            for (int i = 0; i < 4; i++)
#pragma unroll
                for (int j = 0; j < 4; j++)
                    acc[i][j] = __builtin_amdgcn_mfma_f32_16x16x32_bf16(af[i], bfr[j], acc[i][j], 0, 0, 0);
        }
    }

    // ---- epilogue: D[row=o][col=m]; col = lane&15, row = quad*4 + reg ----
    const int hh = h0 + wm;
#pragma unroll
    for (int i = 0; i < 4; i++) {
        const int obase = o_blk + wo * 64 + i * 16 + quad * 4;
#pragma unroll
        for (int j = 0; j < 4; j++) {
            const int w = j * 16 + lrow;
            if (w < HW) {
#pragma unroll
                for (int rg = 0; rg < 4; ++rg) {
                    const int o = obase + rg;
                    out[(((size_t)b * O_CH + o) * HW + hh) * HW + w] = acc[i][j][rg] + bias[o];
                }
            }
        }
    }
}

extern "C" void kernel_launch(void* const* d_in, const int* in_sizes, int n_in,
                              void* d_out, int out_size, void* d_ws, size_t ws_size,
                              hipStream_t stream) {
    const float* x     = (const float*)d_in[0];
    const float* pcilt = (const float*)d_in[1];
    const float* bias  = (const float*)d_in[2];
    float* out = (float*)d_out;

    u16* xp = (u16*)d_ws;                                   // 16*58*72*128 u16 = 17.1 MB
    u16* Bq = xp + (size_t)B_N * PH * PW * C_CH;            // 9*256*128 u16   = 0.6 MB

    quant_pad<<<dim3(PH, B_N), 256, 0, stream>>>(x, xp);
    make_w<<<(9 * O_CH * C_CH) / 256, 256, 0, stream>>>(pcilt, Bq);
    conv_mfma<<<dim3(O_CH / 128, HW / 2, B_N), dim3(256), 0, stream>>>(xp, Bq, bias, out);
}

// Round 3
// 411.067 us; speedup vs baseline: 1.1078x; 1.1078x over previous
//
#include <hip/hip_runtime.h>
#include <stdint.h>

typedef unsigned short u16;
typedef __bf16 bf16x8 __attribute__((ext_vector_type(8)));
typedef float f32x4 __attribute__((ext_vector_type(4)));
typedef unsigned short u16x4 __attribute__((ext_vector_type(4)));
typedef unsigned short u16x8 __attribute__((ext_vector_type(8)));

#define B_N   16
#define C_CH  128
#define O_CH  256
#define HW    56
#define PH    58
#define PW    72
#define NCG   16          // groups of 8 channels

#define GLOBAL_AS __attribute__((address_space(1)))
#define LDS_AS    __attribute__((address_space(3)))

__device__ __forceinline__ void glds16(const u16* g, u16* l) {
    __builtin_amdgcn_global_load_lds((const GLOBAL_AS void*)g, (LDS_AS void*)l, 16, 0, 0);
}

// ---------------------------------------------------------------------------
// prep1: quantize + pad + re-block NCHW -> xq[b][hp][cg][wp][c8] (bf16 bits).
// A (cg, wp-run) row is contiguous: the conv kernel's glds reads 1 KB
// contiguous segments (64 wp x 8 c8 = 8 cachelines). One block per (b,hp).
// ---------------------------------------------------------------------------
__global__ __launch_bounds__(256) void quant_pad(const float* __restrict__ x,
                                                 u16* __restrict__ xq) {
    __shared__ u16 Lt[C_CH][57];                 // [c][w], 57 w-slots vs bank conflicts
    const int hp = blockIdx.x;
    const int b = blockIdx.y;
    const int tid = threadIdx.x;
    const int h = hp - 1;
    const bool interior = (unsigned)h < HW;

    if (interior) {
        const float* xr = x + ((size_t)b * C_CH * HW + h) * HW;   // + c*HW*HW + w
        for (int i = 0; i < 7; ++i) {            // 1792 float4 units = 128c x 14
            int u = i * 256 + tid;
            int c = u / 14, w4 = u % 14;
            float4 v = *(const float4*)(xr + (size_t)c * (HW * HW) + w4 * 4);
            float q0 = fminf(fmaxf(rintf(v.x * 255.0f), 0.0f), 255.0f);
            float q1 = fminf(fmaxf(rintf(v.y * 255.0f), 0.0f), 255.0f);
            float q2 = fminf(fmaxf(rintf(v.z * 255.0f), 0.0f), 255.0f);
            float q3 = fminf(fmaxf(rintf(v.w * 255.0f), 0.0f), 255.0f);
            Lt[c][w4 * 4 + 0] = (u16)(__float_as_uint(q0) >> 16);
            Lt[c][w4 * 4 + 1] = (u16)(__float_as_uint(q1) >> 16);
            Lt[c][w4 * 4 + 2] = (u16)(__float_as_uint(q2) >> 16);
            Lt[c][w4 * 4 + 3] = (u16)(__float_as_uint(q3) >> 16);
        }
    }
    __syncthreads();
    // write xq row for (b,hp): 16 cg x 72 wp x 8 c8 = 9216 u16 = 2304 u16x4
    u16* dst = xq + (size_t)(b * PH + hp) * (NCG * PW * 8);
    for (int j = 0; j < 9; ++j) {
        int u = j * 256 + tid;
        int c8b = (u & 1) * 4;
        int wp = (u >> 1) % PW;
        int cg = u / (2 * PW);
        int w = wp - 1;
        u16x4 v = (u16x4){0, 0, 0, 0};
        if (interior && (unsigned)w < HW) {
#pragma unroll
            for (int e = 0; e < 4; ++e) v[e] = Lt[cg * 8 + c8b + e][w];
        }
        *(u16x4*)(dst + (size_t)u * 4) = v;
    }
}

// ---------------------------------------------------------------------------
// prep2: Bw[r][cg][o][c8] = bf16bits( pcilt[o][cg*8+c8][r][1] ),  r = kh*3+kw.
// o-runs are contiguous so conv weight loads coalesce per quad.
// ---------------------------------------------------------------------------
__global__ __launch_bounds__(256) void make_w(const float* __restrict__ pcilt,
                                              u16* __restrict__ Bw) {
    int u = blockIdx.x * 256 + threadIdx.x;      // 36864 u16x8 units
    int o = u & 255;
    int cg = (u >> 8) & 15;
    int r = u >> 12;
    const float* src = pcilt + ((size_t)(o * C_CH + cg * 8) * 9 + r) * 256 + 1;
    u16x8 v;
#pragma unroll
    for (int e = 0; e < 8; ++e)
        v[e] = (u16)(__float_as_uint(src[(size_t)e * (9 * 256)]) >> 16);
    *(u16x8*)(Bw + (size_t)u * 8) = v;
}

// ---------------------------------------------------------------------------
// conv as implicit GEMM:  D[o][m] = sum_k W[o][k] * Im[k][m]
// Block: 128 o x 128 m (m = dh*64 + w_out), 4 waves 2x2. BK=64 per stage
// (18 stages, 36 barriers). Is staged via contiguous 1 KB glds16; weights
// loaded direct to VGPRs (L2-resident), issued before the barrier drain.
// ---------------------------------------------------------------------------
__global__ __launch_bounds__(256) void conv_mfma(const u16* __restrict__ xq,
                                                 const u16* __restrict__ Bw,
                                                 const float* __restrict__ bias,
                                                 float* __restrict__ out) {
    __shared__ __align__(16) u16 Is[8][128][8];   // [octet][m][c8]  16 KB

    const int tid = threadIdx.x;
    const int o_blk = blockIdx.x * 128;
    const int h0 = blockIdx.y * 2;
    const int b = blockIdx.z;

    const int lane = tid & 63;
    const int wid = tid >> 6;
    const int wo = wid & 1;
    const int wm = wid >> 1;
    const int quad = lane >> 4;
    const int lrow = lane & 15;

    f32x4 acc[4][4];
#pragma unroll
    for (int i = 0; i < 4; i++)
#pragma unroll
        for (int j = 0; j < 4; j++) acc[i][j] = (f32x4){0.f, 0.f, 0.f, 0.f};

    // per-lane weight base: element ((r16cg)*256 + o_blk + wo*64 + i*16 + lrow)*8
    const u16* wbase = Bw + (size_t)(o_blk + wo * 64 + lrow) * 8;

    for (int r = 0; r < 9; ++r) {
        const int kh = r / 3, kw = r % 3;
#pragma unroll
        for (int half = 0; half < 2; ++half) {
            __syncthreads();
            // ---- stage Is: wave wid covers octets {wid, wid+4} x dh {0,1} ----
#pragma unroll
            for (int gg = 0; gg < 2; ++gg) {
                const int g = wid + gg * 4;                    // octet 0..7
                const int cg = half * 8 + g;
#pragma unroll
                for (int dh = 0; dh < 2; ++dh) {
                    const u16* src = xq +
                        ((size_t)((b * PH + h0 + dh + kh) * NCG + cg) * PW + kw + lane) * 8;
                    glds16(src, &Is[g][dh * 64][0]);
                }
            }
            // ---- weight fragments direct to VGPR (issue before the drain) ----
            bf16x8 af[2][4];
#pragma unroll
            for (int s = 0; s < 2; ++s) {
                const int cgw = r * 16 + half * 8 + s * 4 + quad;
#pragma unroll
                for (int i = 0; i < 4; ++i)
                    af[s][i] = *(const bf16x8*)(wbase + ((size_t)cgw * 256 + i * 16) * 8);
            }
            __syncthreads();
            // ---- compute ----
            bf16x8 bfr[2][4];
#pragma unroll
            for (int s = 0; s < 2; ++s)
#pragma unroll
                for (int j = 0; j < 4; ++j)
                    bfr[s][j] = *(const bf16x8*)&Is[s * 4 + quad][wm * 64 + j * 16 + lrow][0];
#pragma unroll
            for (int s = 0; s < 2; ++s)
#pragma unroll
                for (int i = 0; i < 4; ++i)
#pragma unroll
                    for (int j = 0; j < 4; ++j)
                        acc[i][j] = __builtin_amdgcn_mfma_f32_16x16x32_bf16(af[s][i], bfr[s][j], acc[i][j], 0, 0, 0);
        }
    }

    // ---- epilogue: D[row=o][col=m]; col = lane&15, row = quad*4 + reg ----
    const int hh = h0 + wm;
#pragma unroll
    for (int i = 0; i < 4; i++) {
        const int obase = o_blk + wo * 64 + i * 16 + quad * 4;
#pragma unroll
        for (int j = 0; j < 4; j++) {
            const int w = j * 16 + lrow;
            if (w < HW) {
#pragma unroll
                for (int rg = 0; rg < 4; ++rg) {
                    const int o = obase + rg;
                    out[(((size_t)b * O_CH + o) * HW + hh) * HW + w] = acc[i][j][rg] + bias[o];
                }
            }
        }
    }
}

extern "C" void kernel_launch(void* const* d_in, const int* in_sizes, int n_in,
                              void* d_out, int out_size, void* d_ws, size_t ws_size,
                              hipStream_t stream) {
    const float* x     = (const float*)d_in[0];
    const float* pcilt = (const float*)d_in[1];
    const float* bias  = (const float*)d_in[2];
    float* out = (float*)d_out;

    u16* xq = (u16*)d_ws;                                   // 16*58*16*72*8 u16 = 17.1 MB
    u16* Bw = xq + (size_t)B_N * PH * NCG * PW * 8;         // 9*16*256*8 u16  = 0.6 MB

    quant_pad<<<dim3(PH, B_N), 256, 0, stream>>>(x, xq);
    make_w<<<(9 * NCG * O_CH * 8) / (8 * 256), 256, 0, stream>>>(pcilt, Bw);
    conv_mfma<<<dim3(O_CH / 128, HW / 2, B_N), dim3(256), 0, stream>>>(xq, Bw, bias, out);
}